// Round 5
// baseline (466.729 us; speedup 1.0000x reference)
//
#include <hip/hip_runtime.h>
#include <hip/hip_bf16.h>
#include <stdint.h>

#define M_DIM 4096
#define N_DIM 11008
#define K_DIM 4096
#define KP    (K_DIM / 2)   // packed int32s per weight row

typedef __attribute__((ext_vector_type(4))) float f32x4;
typedef __attribute__((ext_vector_type(8))) short short8;

#define AS1 __attribute__((address_space(1)))
#define AS3 __attribute__((address_space(3)))

static __device__ __forceinline__ unsigned short f32_to_bf16(float f) {
  union { float f; unsigned int u; } v; v.f = f;
  unsigned int r = v.u + (0x7FFFu + ((v.u >> 16) & 1u));  // round-to-nearest-even
  return (unsigned short)(r >> 16);
}

// ---------------- Pass 1: dequant packed int32 nibbles -> W bf16 [N][K] ----------------
__global__ __launch_bounds__(256) void dequant_w(const int* __restrict__ pw,
                                                 const float* __restrict__ sc,
                                                 const float* __restrict__ zp,
                                                 unsigned short* __restrict__ wb) {
  const int total = (N_DIM * KP) / 4;  // 4 int32 -> 8 bf16 per item
  for (int i = blockIdx.x * 256 + threadIdx.x; i < total; i += gridDim.x * 256) {
    int4 p = ((const int4*)pw)[i];
    int row = i >> 9;                  // 512 uint4 per row
    float s = sc[row], z = zp[row];
    int v[4] = {p.x, p.y, p.z, p.w};
    unsigned short o[8];
#pragma unroll
    for (int j = 0; j < 4; ++j) {
      o[2 * j]     = f32_to_bf16(((float)(v[j] & 15) - z) * s);
      o[2 * j + 1] = f32_to_bf16(((float)((v[j] >> 4) & 15) - z) * s);
    }
    uint4 st;
    st.x = (unsigned)o[0] | ((unsigned)o[1] << 16);
    st.y = (unsigned)o[2] | ((unsigned)o[3] << 16);
    st.z = (unsigned)o[4] | ((unsigned)o[5] << 16);
    st.w = (unsigned)o[6] | ((unsigned)o[7] << 16);
    ((uint4*)wb)[i] = st;
  }
}

// ---------------- Pass 2: x fp32 -> bf16 [M][K] ----------------
__global__ __launch_bounds__(256) void conv_x(const float* __restrict__ x,
                                              unsigned short* __restrict__ xb) {
  const int total = (M_DIM * K_DIM) / 8;
  for (int i = blockIdx.x * 256 + threadIdx.x; i < total; i += gridDim.x * 256) {
    float4 a = ((const float4*)x)[2 * i];
    float4 b = ((const float4*)x)[2 * i + 1];
    uint4 st;
    st.x = (unsigned)f32_to_bf16(a.x) | ((unsigned)f32_to_bf16(a.y) << 16);
    st.y = (unsigned)f32_to_bf16(a.z) | ((unsigned)f32_to_bf16(a.w) << 16);
    st.z = (unsigned)f32_to_bf16(b.x) | ((unsigned)f32_to_bf16(b.y) << 16);
    st.w = (unsigned)f32_to_bf16(b.z) | ((unsigned)f32_to_bf16(b.w) << 16);
    ((uint4*)xb)[i] = st;
  }
}

// ---------------- Main: 256x256 tile, BK=64, 8-phase pipelined bf16 MFMA GEMM ----------------
// C[M,N] = Xb[M,K] @ Wb[N,K]^T.  8 waves (2M x 4N), per-wave output 128x64.
// LDS: 8 half-slots x 16 KiB: slot = parity*4 + role {0:B0,1:B1,2:A0,3:A1}.
// Half layout: row-major [128 rows][64 k] bf16 with 16B-chunk XOR swizzle:
//   LDS slot (row, j) holds global chunk (row, j ^ (row&7)).   (involution)
// Staging: LDS dst linear (m104), global src pre-swizzled -> coalesced (R4: +25%).
// Reads: slot j = g ^ (lr&7) -> 2 lanes/bank = free (0 conflicts, R2-R4).
// R5 change: ALL 24 fragment ds_read_b128 of a K-tile hoisted to tile top, so the
// LDS pipe drains them under P1-P3's MFMA windows (R4 serialized reads vs MFMA ->
// 47% MfmaUtil matched the serialization model). Stages/barriers/vmcnt frozen from R4:
// stage A(t+1) at P1/P2, B(t+2) at P3/P4; vmcnt(4) once per K-tile at P4; 2 barriers
// per phase; setprio(1) around MFMA.
#define BM 256
#define BN 256
#define BK 64
#define NTILE (K_DIM / BK)      // 64
#define NT_M (M_DIM / BM)       // 16
#define NT_N (N_DIM / BN)       // 43
#define NWG  (NT_M * NT_N)      // 688 (div by 8 -> XCD swizzle bijective)

#define WAITV(n) asm volatile("s_waitcnt vmcnt(" #n ")" ::: "memory")
#define BARR     do { asm volatile("" ::: "memory"); __builtin_amdgcn_s_barrier(); asm volatile("" ::: "memory"); } while (0)

__global__ __launch_bounds__(512, 2) void gemm_bt(const unsigned short* __restrict__ Xb,
                                                  const unsigned short* __restrict__ Wb,
                                                  float* __restrict__ C) {
  __shared__ __align__(16) unsigned short lds[65536];  // 128 KiB, 8 x 8192-ushort half-slots

  const int t = threadIdx.x;
  const int bid = blockIdx.x;
  const int swz = (bid & 7) * (NWG / 8) + (bid >> 3);  // T1 XCD swizzle
  const int tm = swz & 15;   // M-tile
  const int tn = swz >> 4;   // N-tile (consecutive swz share the W-panel)

  // --- stage sources: thread t owns LDS chunks c0=t (rows 0..63) and c1=t+512 (rows 64..127)
  // of each half. row = c>>3, slot j = c&7, global chunk g = j ^ (row&7)  (c1: same g, row+64).
  const int srow = t >> 3;                       // 0..63
  const int g0 = (t & 7) ^ (srow & 7);           // pre-swizzled global chunk
  const int koff = g0 * 8;                       // ushort offset within K-tile
  const unsigned short* pB0c0 = Wb + (size_t)(tn * BN + srow) * K_DIM + koff;
  const unsigned short* pB0c1 = Wb + (size_t)(tn * BN + 64 + srow) * K_DIM + koff;
  const unsigned short* pB1c0 = Wb + (size_t)(tn * BN + 128 + srow) * K_DIM + koff;
  const unsigned short* pB1c1 = Wb + (size_t)(tn * BN + 192 + srow) * K_DIM + koff;
  const unsigned short* pA0c0 = Xb + (size_t)(tm * BM + srow) * K_DIM + koff;
  const unsigned short* pA0c1 = Xb + (size_t)(tm * BM + 64 + srow) * K_DIM + koff;
  const unsigned short* pA1c0 = Xb + (size_t)(tm * BM + 128 + srow) * K_DIM + koff;
  const unsigned short* pA1c1 = Xb + (size_t)(tm * BM + 192 + srow) * K_DIM + koff;
  const int d0 = t * 8;            // LDS ushort offset of chunk c0 within a half-slot (linear)
  const int d1 = d0 + 4096;        // chunk c1

  // --- wave / lane geometry
  const int lane = t & 63;
  const int w = t >> 6;
  const int wm = w >> 2;          // 0..1 -> rows wm*128..+127  (A-half = wm)
  const int wn = w & 3;           // 0..3 -> cols wn*64..+63    (B-half = wn>>1)
  const int lr = lane & 15, lk = lane >> 4;

  // fragment read bases (ushort units within the 8-slot LDS; add P*32768 + mloc/n*1024).
  // addr = halfbase + row*64 + j*8, row = mloc*16+lr, j = (kk*4+lk) ^ (lr&7).
  const int j0 = lk ^ (lr & 7);
  const int aB0 = (2 + wm) * 8192 + lr * 64 + j0 * 8;  // kk=0
  const int aB1 = aB0 ^ 32;                            // kk=1 (j ^= 4)
  const int bB0 = (wn >> 1) * 8192 + (wn & 1) * 4096 + lr * 64 + j0 * 8;
  const int bB1 = bB0 ^ 32;

  f32x4 acc[8][4] = {};

#define GLL(src, dstoff) \
  __builtin_amdgcn_global_load_lds((const AS1 void*)(src), (AS3 void*)(lds + (dstoff)), 16, 0, 0)

  // ---- prologue: stage 6 halves: B0,B1,A0,A1 of tile0 (parity0), B0,B1 of tile1 (parity1)
  GLL(pB0c0, 0 * 8192 + d0); GLL(pB0c1, 0 * 8192 + d1);
  GLL(pB1c0, 1 * 8192 + d0); GLL(pB1c1, 1 * 8192 + d1);
  GLL(pA0c0, 2 * 8192 + d0); GLL(pA0c1, 2 * 8192 + d1);
  GLL(pA1c0, 3 * 8192 + d0); GLL(pA1c1, 3 * 8192 + d1);
  GLL(pB0c0 + BK, 4 * 8192 + d0); GLL(pB0c1 + BK, 4 * 8192 + d1);
  GLL(pB1c0 + BK, 5 * 8192 + d0); GLL(pB1c1 + BK, 5 * 8192 + d1);
  pB0c0 += 2 * BK; pB0c1 += 2 * BK; pB1c0 += 2 * BK; pB1c1 += 2 * BK;  // next B stage: tile 2
  pA0c0 += BK;     pA0c1 += BK;     pA1c0 += BK;     pA1c1 += BK;      // next A stage: tile 1
  WAITV(4);  // retire halves 0..3 (all of tile 0); B(tile1) stays in flight
  BARR;

  // VMODE: 0 -> vmcnt(4), 1 -> vmcnt(0), 2 -> none
#define TILE(P, SA, SB, VMODE) do {                                                        \
    short8 a0[4], a1[4], a2[4], a3[4], b0[4], b1[4];                                       \
    /* ---- hoisted K-tile fragment reads, in use-order ---- */                            \
    _Pragma("unroll") for (int i = 0; i < 4; ++i)                                          \
      a0[i] = *(const short8*)(lds + (P) * 32768 + aB0 + i * 1024);                        \
    _Pragma("unroll") for (int n = 0; n < 4; ++n)                                          \
      b0[n] = *(const short8*)(lds + (P) * 32768 + bB0 + n * 1024);                        \
    _Pragma("unroll") for (int i = 0; i < 4; ++i)                                          \
      a1[i] = *(const short8*)(lds + (P) * 32768 + aB0 + (4 + i) * 1024);                  \
    _Pragma("unroll") for (int n = 0; n < 4; ++n)                                          \
      b1[n] = *(const short8*)(lds + (P) * 32768 + bB1 + n * 1024);                        \
    _Pragma("unroll") for (int i = 0; i < 4; ++i)                                          \
      a2[i] = *(const short8*)(lds + (P) * 32768 + aB1 + i * 1024);                        \
    _Pragma("unroll") for (int i = 0; i < 4; ++i)                                          \
      a3[i] = *(const short8*)(lds + (P) * 32768 + aB1 + (4 + i) * 1024);                  \
    /* ---- P1: MFMA a0 x b0 ---- */                                                       \
    if (SA) { GLL(pA0c0, (((P) ^ 1) * 4 + 2) * 8192 + d0);                                 \
              GLL(pA0c1, (((P) ^ 1) * 4 + 2) * 8192 + d1);                                 \
              pA0c0 += BK; pA0c1 += BK; }                                                  \
    BARR;                                                                                  \
    __builtin_amdgcn_s_setprio(1);                                                         \
    _Pragma("unroll") for (int i = 0; i < 4; ++i)                                          \
      _Pragma("unroll") for (int n = 0; n < 4; ++n)                                        \
        acc[i][n] = __builtin_amdgcn_mfma_f32_16x16x32_bf16(a0[i], b0[n], acc[i][n], 0, 0, 0); \
    __builtin_amdgcn_s_setprio(0);                                                         \
    BARR;                                                                                  \
    /* ---- P2: MFMA a1 x b0 ---- */                                                       \
    if (SA) { GLL(pA1c0, (((P) ^ 1) * 4 + 3) * 8192 + d0);                                 \
              GLL(pA1c1, (((P) ^ 1) * 4 + 3) * 8192 + d1);                                 \
              pA1c0 += BK; pA1c1 += BK; }                                                  \
    BARR;                                                                                  \
    __builtin_amdgcn_s_setprio(1);                                                         \
    _Pragma("unroll") for (int i = 0; i < 4; ++i)                                          \
      _Pragma("unroll") for (int n = 0; n < 4; ++n)                                        \
        acc[4 + i][n] = __builtin_amdgcn_mfma_f32_16x16x32_bf16(a1[i], b0[n], acc[4 + i][n], 0, 0, 0); \
    __builtin_amdgcn_s_setprio(0);                                                         \
    BARR;                                                                                  \
    /* ---- P3: MFMA a2 x b1 ---- */                                                       \
    if (SB) { GLL(pB0c0, ((P) * 4 + 0) * 8192 + d0);                                       \
              GLL(pB0c1, ((P) * 4 + 0) * 8192 + d1);                                       \
              pB0c0 += BK; pB0c1 += BK; }                                                  \
    BARR;                                                                                  \
    __builtin_amdgcn_s_setprio(1);                                                         \
    _Pragma("unroll") for (int i = 0; i < 4; ++i)                                          \
      _Pragma("unroll") for (int n = 0; n < 4; ++n)                                        \
        acc[i][n] = __builtin_amdgcn_mfma_f32_16x16x32_bf16(a2[i], b1[n], acc[i][n], 0, 0, 0); \
    __builtin_amdgcn_s_setprio(0);                                                         \
    BARR;                                                                                  \
    /* ---- P4: MFMA a3 x b1 ---- */                                                       \
    if (SB) { GLL(pB1c0, ((P) * 4 + 1) * 8192 + d0);                                       \
              GLL(pB1c1, ((P) * 4 + 1) * 8192 + d1);                                       \
              pB1c0 += BK; pB1c1 += BK; }                                                  \
    if ((VMODE) == 0) { WAITV(4); } else if ((VMODE) == 1) { WAITV(0); }                   \
    BARR;                                                                                  \
    __builtin_amdgcn_s_setprio(1);                                                         \
    _Pragma("unroll") for (int i = 0; i < 4; ++i)                                          \
      _Pragma("unroll") for (int n = 0; n < 4; ++n)                                        \
        acc[4 + i][n] = __builtin_amdgcn_mfma_f32_16x16x32_bf16(a3[i], b1[n], acc[4 + i][n], 0, 0, 0); \
    __builtin_amdgcn_s_setprio(0);                                                         \
    BARR;                                                                                  \
  } while (0)

  // main loop: tiles 0..61
  for (int it = 0; it < (NTILE - 2) / 2; ++it) {
    TILE(0, 1, 1, 0);
    TILE(1, 1, 1, 0);
  }
  TILE(0, 1, 0, 1);   // tile 62: stage A(63) only; drain everything
  TILE(1, 0, 0, 2);   // tile 63: no stage, no wait

#undef TILE
#undef GLL

  // epilogue: C/D layout col=lane&15, row=(lane>>4)*4+reg (validated R1-R4)
  const int row0 = tm * BM + wm * 128 + lk * 4;
  const int col0 = tn * BN + wn * 64 + lr;
#pragma unroll
  for (int m = 0; m < 8; ++m)
#pragma unroll
    for (int n = 0; n < 4; ++n)
#pragma unroll
      for (int rr = 0; rr < 4; ++rr)
        C[(size_t)(row0 + m * 16 + rr) * N_DIM + col0 + n * 16] = acc[m][n][rr];
}

// ---------------- Fallback: fp32 LDS-tiled GEMM reading packed weights (ws too small) ----------------
__global__ __launch_bounds__(256) void fallback_gemm(const float* __restrict__ x,
                                                     const int* __restrict__ pw,
                                                     const float* __restrict__ sc,
                                                     const float* __restrict__ zp,
                                                     float* __restrict__ out) {
  __shared__ float Xs[64][33];
  __shared__ float Ws[64][33];
  const int bid = blockIdx.x;
  const int bm = bid & 63;
  const int bn = bid >> 6;
  const int t = threadIdx.x;
  const int tx = t & 15, ty = t >> 4;
  float acc[4][4] = {};
  for (int k0 = 0; k0 < K_DIM; k0 += 32) {
    __syncthreads();
#pragma unroll
    for (int i = 0; i < 8; ++i) {
      int e = t + i * 256; int r = e >> 5, c = e & 31;
      Xs[r][c] = x[(size_t)(bm * 64 + r) * K_DIM + k0 + c];
    }
#pragma unroll
    for (int i = 0; i < 4; ++i) {
      int e = t + i * 256; int rr = e >> 4, jj = e & 15;
      int row = bn * 64 + rr;
      int v = pw[(size_t)row * KP + (k0 >> 1) + jj];
      float s = sc[row], z = zp[row];
      Ws[rr][2 * jj]     = ((float)(v & 15) - z) * s;
      Ws[rr][2 * jj + 1] = ((float)((v >> 4) & 15) - z) * s;
    }
    __syncthreads();
#pragma unroll
    for (int kk = 0; kk < 32; ++kk) {
      float a[4], b[4];
#pragma unroll
      for (int i2 = 0; i2 < 4; ++i2) a[i2] = Xs[ty * 4 + i2][kk];
#pragma unroll
      for (int j2 = 0; j2 < 4; ++j2) b[j2] = Ws[tx * 4 + j2][kk];
#pragma unroll
      for (int i2 = 0; i2 < 4; ++i2)
#pragma unroll
        for (int j2 = 0; j2 < 4; ++j2) acc[i2][j2] += a[i2] * b[j2];
    }
  }
#pragma unroll
  for (int i2 = 0; i2 < 4; ++i2)
#pragma unroll
    for (int j2 = 0; j2 < 4; ++j2)
      out[(size_t)(bm * 64 + ty * 4 + i2) * N_DIM + bn * 64 + tx * 4 + j2] = acc[i2][j2];
}

extern "C" void kernel_launch(void* const* d_in, const int* in_sizes, int n_in,
                              void* d_out, int out_size, void* d_ws, size_t ws_size,
                              hipStream_t stream) {
  const float* x  = (const float*)d_in[0];
  const int*   pw = (const int*)d_in[1];
  const float* sc = (const float*)d_in[2];
  const float* zp = (const float*)d_in[3];
  float* out = (float*)d_out;

  const size_t wb_bytes = (size_t)N_DIM * K_DIM * 2;
  const size_t xb_bytes = (size_t)M_DIM * K_DIM * 2;

  if (ws_size >= wb_bytes + xb_bytes) {
    unsigned short* wb = (unsigned short*)d_ws;
    unsigned short* xb = (unsigned short*)((char*)d_ws + wb_bytes);
    hipLaunchKernelGGL(dequant_w, dim3(2048), dim3(256), 0, stream, pw, sc, zp, wb);
    hipLaunchKernelGGL(conv_x,    dim3(2048), dim3(256), 0, stream, x, xb);
    hipLaunchKernelGGL(gemm_bt,   dim3(NWG),  dim3(512), 0, stream, xb, wb, out);
  } else {
    hipLaunchKernelGGL(fallback_gemm, dim3(64 * 172), dim3(256), 0, stream, x, pw, sc, zp, out);
  }
}

// Round 6
// 363.347 us; speedup vs baseline: 1.2845x; 1.2845x over previous
//
#include <hip/hip_runtime.h>
#include <hip/hip_bf16.h>
#include <stdint.h>

#define M_DIM 4096
#define N_DIM 11008
#define K_DIM 4096
#define KP    (K_DIM / 2)   // packed int32s per weight row

typedef __attribute__((ext_vector_type(4))) float f32x4;
typedef __attribute__((ext_vector_type(8))) short short8;

#define AS1 __attribute__((address_space(1)))
#define AS3 __attribute__((address_space(3)))

static __device__ __forceinline__ unsigned short f32_to_bf16(float f) {
  union { float f; unsigned int u; } v; v.f = f;
  unsigned int r = v.u + (0x7FFFu + ((v.u >> 16) & 1u));  // round-to-nearest-even
  return (unsigned short)(r >> 16);
}

// ---------------- Pass 1: dequant packed int32 nibbles -> W bf16 [N][K] ----------------
__global__ __launch_bounds__(256) void dequant_w(const int* __restrict__ pw,
                                                 const float* __restrict__ sc,
                                                 const float* __restrict__ zp,
                                                 unsigned short* __restrict__ wb) {
  const int total = (N_DIM * KP) / 4;  // 4 int32 -> 8 bf16 per item
  for (int i = blockIdx.x * 256 + threadIdx.x; i < total; i += gridDim.x * 256) {
    int4 p = ((const int4*)pw)[i];
    int row = i >> 9;                  // 512 uint4 per row
    float s = sc[row], z = zp[row];
    int v[4] = {p.x, p.y, p.z, p.w};
    unsigned short o[8];
#pragma unroll
    for (int j = 0; j < 4; ++j) {
      o[2 * j]     = f32_to_bf16(((float)(v[j] & 15) - z) * s);
      o[2 * j + 1] = f32_to_bf16(((float)((v[j] >> 4) & 15) - z) * s);
    }
    uint4 st;
    st.x = (unsigned)o[0] | ((unsigned)o[1] << 16);
    st.y = (unsigned)o[2] | ((unsigned)o[3] << 16);
    st.z = (unsigned)o[4] | ((unsigned)o[5] << 16);
    st.w = (unsigned)o[6] | ((unsigned)o[7] << 16);
    ((uint4*)wb)[i] = st;
  }
}

// ---------------- Pass 2: x fp32 -> bf16 [M][K] ----------------
__global__ __launch_bounds__(256) void conv_x(const float* __restrict__ x,
                                              unsigned short* __restrict__ xb) {
  const int total = (M_DIM * K_DIM) / 8;
  for (int i = blockIdx.x * 256 + threadIdx.x; i < total; i += gridDim.x * 256) {
    float4 a = ((const float4*)x)[2 * i];
    float4 b = ((const float4*)x)[2 * i + 1];
    uint4 st;
    st.x = (unsigned)f32_to_bf16(a.x) | ((unsigned)f32_to_bf16(a.y) << 16);
    st.y = (unsigned)f32_to_bf16(a.z) | ((unsigned)f32_to_bf16(a.w) << 16);
    st.z = (unsigned)f32_to_bf16(b.x) | ((unsigned)f32_to_bf16(b.y) << 16);
    st.w = (unsigned)f32_to_bf16(b.z) | ((unsigned)f32_to_bf16(b.w) << 16);
    ((uint4*)xb)[i] = st;
  }
}

// ---------------- Main: 256x256 tile, BK=64, pipelined bf16 MFMA GEMM ----------------
// C[M,N] = Xb[M,K] @ Wb[N,K]^T.  8 waves (2M x 4N), per-wave output 128x64.
// LDS: 8 half-slots x 16 KiB: slot = parity*4 + role {0:B0,1:B1,2:A0,3:A1}.
// Half layout: row-major [128 rows][64 k] bf16 with 16B-chunk XOR swizzle:
//   LDS slot (row, j) holds global chunk (row, j ^ (row&7)).   (involution)
// Staging: LDS dst linear (m104), global src pre-swizzled -> coalesced (R4).
// Reads: slot j = g ^ (lr&7) -> 2 lanes/bank = free (0 conflicts, R2-R5).
// R6 change: BARRIER DIET. R4's 8 barriers/K-tile kept all waves in sub-phase
// lockstep -> LDS reads and MFMA alternated chip-wide (47% MfmaUtil = serialized
// model). Hazard audit: only TWO fences per K-tile are required:
//   (mid)  after P2's b-reads (+ explicit lgkmcnt(0) so they are retired) and
//          before P3/P4's B(t+2) stages into the same-parity B slots;
//   (end)  WAITV(4) + barrier = collective vmcnt fence (FIFO: retires B(t+1),
//          A(t+1); leaves B(t+2) in flight) before tile t+1's reads.
// A-slot WAR: a3 reads consumed by P4 MFMA before (end); next A-write issues
// after it. A-slot RAW: A(t) retired by t-1's WAITV(4). All unchanged from R4.
// Waves may now skew up to 2 phases -> one wave's ds_reads overlap another's
// MFMA without extra live registers (R5 showed the register cliff at 248/256).
#define BM 256
#define BN 256
#define BK 64
#define NTILE (K_DIM / BK)      // 64
#define NT_M (M_DIM / BM)       // 16
#define NT_N (N_DIM / BN)       // 43
#define NWG  (NT_M * NT_N)      // 688 (div by 8 -> XCD swizzle bijective)

#define WAITV(n) asm volatile("s_waitcnt vmcnt(" #n ")" ::: "memory")
#define WAITL0   asm volatile("s_waitcnt lgkmcnt(0)" ::: "memory")
#define BARR     do { asm volatile("" ::: "memory"); __builtin_amdgcn_s_barrier(); asm volatile("" ::: "memory"); } while (0)

__global__ __launch_bounds__(512, 2) void gemm_bt(const unsigned short* __restrict__ Xb,
                                                  const unsigned short* __restrict__ Wb,
                                                  float* __restrict__ C) {
  __shared__ __align__(16) unsigned short lds[65536];  // 128 KiB, 8 x 8192-ushort half-slots

  const int t = threadIdx.x;
  const int bid = blockIdx.x;
  const int swz = (bid & 7) * (NWG / 8) + (bid >> 3);  // T1 XCD swizzle
  const int tm = swz & 15;   // M-tile
  const int tn = swz >> 4;   // N-tile (consecutive swz share the W-panel)

  // --- stage sources: thread t owns LDS chunks c0=t (rows 0..63) and c1=t+512 (rows 64..127)
  // of each half. row = c>>3, slot j = c&7, global chunk g = j ^ (row&7)  (c1: same g, row+64).
  const int srow = t >> 3;                       // 0..63
  const int g0 = (t & 7) ^ (srow & 7);           // pre-swizzled global chunk
  const int koff = g0 * 8;                       // ushort offset within K-tile
  const unsigned short* pB0c0 = Wb + (size_t)(tn * BN + srow) * K_DIM + koff;
  const unsigned short* pB0c1 = Wb + (size_t)(tn * BN + 64 + srow) * K_DIM + koff;
  const unsigned short* pB1c0 = Wb + (size_t)(tn * BN + 128 + srow) * K_DIM + koff;
  const unsigned short* pB1c1 = Wb + (size_t)(tn * BN + 192 + srow) * K_DIM + koff;
  const unsigned short* pA0c0 = Xb + (size_t)(tm * BM + srow) * K_DIM + koff;
  const unsigned short* pA0c1 = Xb + (size_t)(tm * BM + 64 + srow) * K_DIM + koff;
  const unsigned short* pA1c0 = Xb + (size_t)(tm * BM + 128 + srow) * K_DIM + koff;
  const unsigned short* pA1c1 = Xb + (size_t)(tm * BM + 192 + srow) * K_DIM + koff;
  const int d0 = t * 8;            // LDS ushort offset of chunk c0 within a half-slot (linear)
  const int d1 = d0 + 4096;        // chunk c1

  // --- wave / lane geometry
  const int lane = t & 63;
  const int w = t >> 6;
  const int wm = w >> 2;          // 0..1 -> rows wm*128..+127  (A-half = wm)
  const int wn = w & 3;           // 0..3 -> cols wn*64..+63    (B-half = wn>>1)
  const int lr = lane & 15, lk = lane >> 4;

  // fragment read bases (ushort units within the 8-slot LDS; add P*32768 + mloc/n*1024).
  // addr = halfbase + row*64 + j*8, row = mloc*16+lr, j = (kk*4+lk) ^ (lr&7).
  const int j0 = lk ^ (lr & 7);
  const int aB0 = (2 + wm) * 8192 + lr * 64 + j0 * 8;  // kk=0
  const int aB1 = aB0 ^ 32;                            // kk=1 (j ^= 4)
  const int bB0 = (wn >> 1) * 8192 + (wn & 1) * 4096 + lr * 64 + j0 * 8;
  const int bB1 = bB0 ^ 32;

  f32x4 acc[8][4] = {};

#define GLL(src, dstoff) \
  __builtin_amdgcn_global_load_lds((const AS1 void*)(src), (AS3 void*)(lds + (dstoff)), 16, 0, 0)

  // ---- prologue: stage 6 halves: B0,B1,A0,A1 of tile0 (parity0), B0,B1 of tile1 (parity1)
  GLL(pB0c0, 0 * 8192 + d0); GLL(pB0c1, 0 * 8192 + d1);
  GLL(pB1c0, 1 * 8192 + d0); GLL(pB1c1, 1 * 8192 + d1);
  GLL(pA0c0, 2 * 8192 + d0); GLL(pA0c1, 2 * 8192 + d1);
  GLL(pA1c0, 3 * 8192 + d0); GLL(pA1c1, 3 * 8192 + d1);
  GLL(pB0c0 + BK, 4 * 8192 + d0); GLL(pB0c1 + BK, 4 * 8192 + d1);
  GLL(pB1c0 + BK, 5 * 8192 + d0); GLL(pB1c1 + BK, 5 * 8192 + d1);
  pB0c0 += 2 * BK; pB0c1 += 2 * BK; pB1c0 += 2 * BK; pB1c1 += 2 * BK;  // next B stage: tile 2
  pA0c0 += BK;     pA0c1 += BK;     pA1c0 += BK;     pA1c1 += BK;      // next A stage: tile 1
  WAITV(4);  // retire halves 0..3 (all of tile 0); B(tile1) stays in flight
  BARR;

  // VMODE: 0 -> vmcnt(4), 1 -> vmcnt(0), 2 -> none
#define TILE(P, SA, SB, VMODE) do {                                                        \
    short8 af[4], bf0[4], bf1[4];                                                          \
    /* ---- P1: reads a0,b0; stage A0(t+1); MFMA a0 x b0 ---- */                           \
    _Pragma("unroll") for (int i = 0; i < 4; ++i)                                          \
      af[i] = *(const short8*)(lds + (P) * 32768 + aB0 + i * 1024);                        \
    _Pragma("unroll") for (int n = 0; n < 4; ++n)                                          \
      bf0[n] = *(const short8*)(lds + (P) * 32768 + bB0 + n * 1024);                       \
    if (SA) { GLL(pA0c0, (((P) ^ 1) * 4 + 2) * 8192 + d0);                                 \
              GLL(pA0c1, (((P) ^ 1) * 4 + 2) * 8192 + d1);                                 \
              pA0c0 += BK; pA0c1 += BK; }                                                  \
    __builtin_amdgcn_s_setprio(1);                                                         \
    _Pragma("unroll") for (int i = 0; i < 4; ++i)                                          \
      _Pragma("unroll") for (int n = 0; n < 4; ++n)                                        \
        acc[i][n] = __builtin_amdgcn_mfma_f32_16x16x32_bf16(af[i], bf0[n], acc[i][n], 0, 0, 0); \
    __builtin_amdgcn_s_setprio(0);                                                         \
    /* ---- P2: reads a1,b1; stage A1(t+1); MFMA a1 x b0; lgkm-drain; MID BARRIER ---- */  \
    _Pragma("unroll") for (int i = 0; i < 4; ++i)                                          \
      af[i] = *(const short8*)(lds + (P) * 32768 + aB0 + (4 + i) * 1024);                  \
    _Pragma("unroll") for (int n = 0; n < 4; ++n)                                          \
      bf1[n] = *(const short8*)(lds + (P) * 32768 + bB1 + n * 1024);                       \
    if (SA) { GLL(pA1c0, (((P) ^ 1) * 4 + 3) * 8192 + d0);                                 \
              GLL(pA1c1, (((P) ^ 1) * 4 + 3) * 8192 + d1);                                 \
              pA1c0 += BK; pA1c1 += BK; }                                                  \
    __builtin_amdgcn_s_setprio(1);                                                         \
    _Pragma("unroll") for (int i = 0; i < 4; ++i)                                          \
      _Pragma("unroll") for (int n = 0; n < 4; ++n)                                        \
        acc[4 + i][n] = __builtin_amdgcn_mfma_f32_16x16x32_bf16(af[i], bf0[n], acc[4 + i][n], 0, 0, 0); \
    __builtin_amdgcn_s_setprio(0);                                                         \
    WAITL0;                                                                                \
    BARR;                                                                                  \
    /* ---- P3: reads a2; stage B0(t+2); MFMA a2 x b1 ---- */                              \
    _Pragma("unroll") for (int i = 0; i < 4; ++i)                                          \
      af[i] = *(const short8*)(lds + (P) * 32768 + aB1 + i * 1024);                        \
    if (SB) { GLL(pB0c0, ((P) * 4 + 0) * 8192 + d0);                                       \
              GLL(pB0c1, ((P) * 4 + 0) * 8192 + d1);                                       \
              pB0c0 += BK; pB0c1 += BK; }                                                  \
    __builtin_amdgcn_s_setprio(1);                                                         \
    _Pragma("unroll") for (int i = 0; i < 4; ++i)                                          \
      _Pragma("unroll") for (int n = 0; n < 4; ++n)                                        \
        acc[i][n] = __builtin_amdgcn_mfma_f32_16x16x32_bf16(af[i], bf1[n], acc[i][n], 0, 0, 0); \
    __builtin_amdgcn_s_setprio(0);                                                         \
    /* ---- P4: reads a3; stage B1(t+2); MFMA a3 x b1; WAITV; END BARRIER ---- */          \
    _Pragma("unroll") for (int i = 0; i < 4; ++i)                                          \
      af[i] = *(const short8*)(lds + (P) * 32768 + aB1 + (4 + i) * 1024);                  \
    if (SB) { GLL(pB1c0, ((P) * 4 + 1) * 8192 + d0);                                       \
              GLL(pB1c1, ((P) * 4 + 1) * 8192 + d1);                                       \
              pB1c0 += BK; pB1c1 += BK; }                                                  \
    __builtin_amdgcn_s_setprio(1);                                                         \
    _Pragma("unroll") for (int i = 0; i < 4; ++i)                                          \
      _Pragma("unroll") for (int n = 0; n < 4; ++n)                                        \
        acc[4 + i][n] = __builtin_amdgcn_mfma_f32_16x16x32_bf16(af[i], bf1[n], acc[4 + i][n], 0, 0, 0); \
    __builtin_amdgcn_s_setprio(0);                                                         \
    if ((VMODE) == 0) { WAITV(4); } else if ((VMODE) == 1) { WAITV(0); }                   \
    BARR;                                                                                  \
  } while (0)

  // main loop: tiles 0..61
  for (int it = 0; it < (NTILE - 2) / 2; ++it) {
    TILE(0, 1, 1, 0);
    TILE(1, 1, 1, 0);
  }
  TILE(0, 1, 0, 1);   // tile 62: stage A(63) only; drain everything
  TILE(1, 0, 0, 2);   // tile 63: no stage, no wait

#undef TILE
#undef GLL

  // epilogue: C/D layout col=lane&15, row=(lane>>4)*4+reg (validated R1-R5)
  const int row0 = tm * BM + wm * 128 + lk * 4;
  const int col0 = tn * BN + wn * 64 + lr;
#pragma unroll
  for (int m = 0; m < 8; ++m)
#pragma unroll
    for (int n = 0; n < 4; ++n)
#pragma unroll
      for (int rr = 0; rr < 4; ++rr)
        C[(size_t)(row0 + m * 16 + rr) * N_DIM + col0 + n * 16] = acc[m][n][rr];
}

// ---------------- Fallback: fp32 LDS-tiled GEMM reading packed weights (ws too small) ----------------
__global__ __launch_bounds__(256) void fallback_gemm(const float* __restrict__ x,
                                                     const int* __restrict__ pw,
                                                     const float* __restrict__ sc,
                                                     const float* __restrict__ zp,
                                                     float* __restrict__ out) {
  __shared__ float Xs[64][33];
  __shared__ float Ws[64][33];
  const int bid = blockIdx.x;
  const int bm = bid & 63;
  const int bn = bid >> 6;
  const int t = threadIdx.x;
  const int tx = t & 15, ty = t >> 4;
  float acc[4][4] = {};
  for (int k0 = 0; k0 < K_DIM; k0 += 32) {
    __syncthreads();
#pragma unroll
    for (int i = 0; i < 8; ++i) {
      int e = t + i * 256; int r = e >> 5, c = e & 31;
      Xs[r][c] = x[(size_t)(bm * 64 + r) * K_DIM + k0 + c];
    }
#pragma unroll
    for (int i = 0; i < 4; ++i) {
      int e = t + i * 256; int rr = e >> 4, jj = e & 15;
      int row = bn * 64 + rr;
      int v = pw[(size_t)row * KP + (k0 >> 1) + jj];
      float s = sc[row], z = zp[row];
      Ws[rr][2 * jj]     = ((float)(v & 15) - z) * s;
      Ws[rr][2 * jj + 1] = ((float)((v >> 4) & 15) - z) * s;
    }
    __syncthreads();
#pragma unroll
    for (int kk = 0; kk < 32; ++kk) {
      float a[4], b[4];
#pragma unroll
      for (int i2 = 0; i2 < 4; ++i2) a[i2] = Xs[ty * 4 + i2][kk];
#pragma unroll
      for (int j2 = 0; j2 < 4; ++j2) b[j2] = Ws[tx * 4 + j2][kk];
#pragma unroll
      for (int i2 = 0; i2 < 4; ++i2)
#pragma unroll
        for (int j2 = 0; j2 < 4; ++j2) acc[i2][j2] += a[i2] * b[j2];
    }
  }
#pragma unroll
  for (int i2 = 0; i2 < 4; ++i2)
#pragma unroll
    for (int j2 = 0; j2 < 4; ++j2)
      out[(size_t)(bm * 64 + ty * 4 + i2) * N_DIM + bn * 64 + tx * 4 + j2] = acc[i2][j2];
}

extern "C" void kernel_launch(void* const* d_in, const int* in_sizes, int n_in,
                              void* d_out, int out_size, void* d_ws, size_t ws_size,
                              hipStream_t stream) {
  const float* x  = (const float*)d_in[0];
  const int*   pw = (const int*)d_in[1];
  const float* sc = (const float*)d_in[2];
  const float* zp = (const float*)d_in[3];
  float* out = (float*)d_out;

  const size_t wb_bytes = (size_t)N_DIM * K_DIM * 2;
  const size_t xb_bytes = (size_t)M_DIM * K_DIM * 2;

  if (ws_size >= wb_bytes + xb_bytes) {
    unsigned short* wb = (unsigned short*)d_ws;
    unsigned short* xb = (unsigned short*)((char*)d_ws + wb_bytes);
    hipLaunchKernelGGL(dequant_w, dim3(2048), dim3(256), 0, stream, pw, sc, zp, wb);
    hipLaunchKernelGGL(conv_x,    dim3(2048), dim3(256), 0, stream, x, xb);
    hipLaunchKernelGGL(gemm_bt,   dim3(NWG),  dim3(512), 0, stream, xb, wb, out);
  } else {
    hipLaunchKernelGGL(fallback_gemm, dim3(64 * 172), dim3(256), 0, stream, x, pw, sc, zp, out);
  }
}

// Round 7
// 225.177 us; speedup vs baseline: 2.0727x; 1.6136x over previous
//
#include <hip/hip_runtime.h>
#include <hip/hip_bf16.h>
#include <stdint.h>

#define M_DIM 4096
#define N_DIM 11008
#define K_DIM 4096
#define KP    (K_DIM / 2)   // packed int32s per weight row

typedef __attribute__((ext_vector_type(4))) int i32x4;

#define AS1 __attribute__((address_space(1)))
#define AS3 __attribute__((address_space(3)))

// ---------------- Pass 1: repack nibbles -> q' = 2q-15 as i8 [N][K] ----------------
__global__ __launch_bounds__(256) void pack_q(const int* __restrict__ pw,
                                              signed char* __restrict__ wq) {
  const int total = (N_DIM * KP) / 4;  // int4 items; 4 int32 -> 8 i8
  for (int i = blockIdx.x * 256 + threadIdx.x; i < total; i += gridDim.x * 256) {
    int4 p = ((const int4*)pw)[i];
    int v[4] = {p.x, p.y, p.z, p.w};
    unsigned int u0 = 0, u1 = 0;
#pragma unroll
    for (int j = 0; j < 2; ++j) {
      unsigned int b0 = (unsigned int)(2 * (v[j] & 15) - 15) & 0xFF;
      unsigned int b1 = (unsigned int)(2 * ((v[j] >> 4) & 15) - 15) & 0xFF;
      u0 |= (b0 | (b1 << 8)) << (16 * j);
    }
#pragma unroll
    for (int j = 0; j < 2; ++j) {
      unsigned int b0 = (unsigned int)(2 * (v[2 + j] & 15) - 15) & 0xFF;
      unsigned int b1 = (unsigned int)(2 * ((v[2 + j] >> 4) & 15) - 15) & 0xFF;
      u1 |= (b0 | (b1 << 8)) << (16 * j);
    }
    uint2 st; st.x = u0; st.y = u1;
    ((uint2*)wq)[i] = st;
  }
}

// ---------------- Pass 2: per-row quantize x -> i8, emit r[b]=sum(x), sx[b] ----------------
__global__ __launch_bounds__(256) void quant_x(const float* __restrict__ x,
                                               signed char* __restrict__ xq,
                                               float* __restrict__ r,
                                               float* __restrict__ sx) {
  const int row = blockIdx.x;
  const int t = threadIdx.x;
  const int lane = t & 63, wid = t >> 6;
  const float4* x4 = (const float4*)(x + (size_t)row * K_DIM);
  float4 v[4];
  float am = 0.0f, sm = 0.0f;
#pragma unroll
  for (int i = 0; i < 4; ++i) {
    v[i] = x4[i * 256 + t];
    sm += v[i].x + v[i].y + v[i].z + v[i].w;
    am = fmaxf(am, fmaxf(fmaxf(fabsf(v[i].x), fabsf(v[i].y)),
                         fmaxf(fabsf(v[i].z), fabsf(v[i].w))));
  }
#pragma unroll
  for (int off = 32; off >= 1; off >>= 1) {
    am = fmaxf(am, __shfl_xor(am, off));
    sm += __shfl_xor(sm, off);
  }
  __shared__ float smax[4], ssum[4];
  if (lane == 0) { smax[wid] = am; ssum[wid] = sm; }
  __syncthreads();
  am = fmaxf(fmaxf(smax[0], smax[1]), fmaxf(smax[2], smax[3]));
  sm = ssum[0] + ssum[1] + ssum[2] + ssum[3];
  const float inv = am > 0.0f ? 127.0f / am : 0.0f;
  unsigned int* xo = (unsigned int*)(xq + (size_t)row * K_DIM);
#pragma unroll
  for (int i = 0; i < 4; ++i) {
    int q0 = min(127, max(-127, __float2int_rn(v[i].x * inv)));
    int q1 = min(127, max(-127, __float2int_rn(v[i].y * inv)));
    int q2 = min(127, max(-127, __float2int_rn(v[i].z * inv)));
    int q3 = min(127, max(-127, __float2int_rn(v[i].w * inv)));
    xo[i * 256 + t] = ((unsigned int)q0 & 0xFF) | (((unsigned int)q1 & 0xFF) << 8) |
                      (((unsigned int)q2 & 0xFF) << 16) | (((unsigned int)q3 & 0xFF) << 24);
  }
  if (t == 0) { r[row] = sm; sx[row] = am > 0.0f ? am / 127.0f : 0.0f; }
}

// ---------------- Main: 256x256 tile, BK=128 (i8), pipelined i8 MFMA GEMM ----------------
// G'[M,N] = Xq[M,K] @ Wq[N,K]^T in i32; epilogue applies affine dequant:
//   out = s[o] * (0.5*sx[b]*G' + (7.5 - zp[o])*r[b]).
// Structure = R6 (2 barriers/K-tile, counted vmcnt, setprio), with i8 halving
// bytes/FLOP: LDS 8 half-slots x 16 KiB: slot = parity*4 + role {B0,B1,A0,A1};
// half = [128 rows][128 k] i8, 16B-chunk XOR swizzle (slot j holds chunk j^(row&7)).
// mfma_i32_16x16x64_i8: per-lane A/B frag = 16 contiguous i8 at k = lk*16 (K/4-chunk
// pattern, dtype-analogous to verified bf16/fp8); C/D layout dtype-independent.
#define BM 256
#define BN 256
#define BK 128                  // bytes = i8 elements per K-tile
#define NTILE (K_DIM / BK)      // 32
#define NT_M (M_DIM / BM)       // 16
#define NT_N (N_DIM / BN)       // 43
#define NWG  (NT_M * NT_N)      // 688 (div by 8 -> XCD swizzle bijective)
#define HS 16384                // half-slot bytes
#define PS 65536                // parity stride (4 half-slots)

#define WAITV(n) asm volatile("s_waitcnt vmcnt(" #n ")" ::: "memory")
#define WAITL0   asm volatile("s_waitcnt lgkmcnt(0)" ::: "memory")
#define BARR     do { asm volatile("" ::: "memory"); __builtin_amdgcn_s_barrier(); asm volatile("" ::: "memory"); } while (0)

__global__ __launch_bounds__(512, 2) void gemm_i8(const signed char* __restrict__ Xq,
                                                  const signed char* __restrict__ Wq,
                                                  const float* __restrict__ sc,
                                                  const float* __restrict__ zp,
                                                  const float* __restrict__ rbuf,
                                                  const float* __restrict__ sxbuf,
                                                  float* __restrict__ C) {
  __shared__ __align__(16) unsigned char lds8[131072];  // 128 KiB

  const int t = threadIdx.x;
  const int bid = blockIdx.x;
  const int swz = (bid & 7) * (NWG / 8) + (bid >> 3);  // T1 XCD swizzle
  const int tm = swz & 15;   // M-tile
  const int tn = swz >> 4;   // N-tile

  // --- stage sources: thread t owns LDS chunks c0=t (rows 0..63) and c1=t+512 (rows 64..127).
  // chunk c: row = c>>3, slot j = c&7, global chunk g = j ^ (row&7); 16 B per chunk.
  const int srow = t >> 3;
  const int g0 = (t & 7) ^ (srow & 7);
  const int koff = g0 * 16;                      // BYTE offset within K-tile
  const signed char* pB0c0 = Wq + (size_t)(tn * BN + srow) * K_DIM + koff;
  const signed char* pB0c1 = Wq + (size_t)(tn * BN + 64 + srow) * K_DIM + koff;
  const signed char* pB1c0 = Wq + (size_t)(tn * BN + 128 + srow) * K_DIM + koff;
  const signed char* pB1c1 = Wq + (size_t)(tn * BN + 192 + srow) * K_DIM + koff;
  const signed char* pA0c0 = Xq + (size_t)(tm * BM + srow) * K_DIM + koff;
  const signed char* pA0c1 = Xq + (size_t)(tm * BM + 64 + srow) * K_DIM + koff;
  const signed char* pA1c0 = Xq + (size_t)(tm * BM + 128 + srow) * K_DIM + koff;
  const signed char* pA1c1 = Xq + (size_t)(tm * BM + 192 + srow) * K_DIM + koff;
  const int d0 = t * 16;           // linear LDS byte offset of chunk c0 (m104 rule)
  const int d1 = d0 + 8192;        // chunk c1

  // --- wave / lane geometry (identical to R6)
  const int lane = t & 63;
  const int w = t >> 6;
  const int wm = w >> 2;          // A-half
  const int wn = w & 3;           // B col group; B-half = wn>>1
  const int lr = lane & 15, lk = lane >> 4;

  // fragment read bases (BYTES). row stride 128 B; frag (row=16m+lr, chunk g=ks*4+lk)
  // at slot j = g ^ (lr&7); ks=1 flips chunk bit2 -> addr ^ 64.
  const int j0 = lk ^ (lr & 7);
  const int aB0 = (2 + wm) * HS + lr * 128 + j0 * 16;
  const int aB1 = aB0 ^ 64;
  const int bB0 = (wn >> 1) * HS + (wn & 1) * 8192 + lr * 128 + j0 * 16;
  const int bB1 = bB0 ^ 64;

  i32x4 acc[8][4] = {};

#define GLL(src, dstoff) \
  __builtin_amdgcn_global_load_lds((const AS1 void*)(src), (AS3 void*)(lds8 + (dstoff)), 16, 0, 0)

  // ---- prologue: stage B0,B1,A0,A1 of tile0 (parity0), B0,B1 of tile1 (parity1)
  GLL(pB0c0, 0 * HS + d0); GLL(pB0c1, 0 * HS + d1);
  GLL(pB1c0, 1 * HS + d0); GLL(pB1c1, 1 * HS + d1);
  GLL(pA0c0, 2 * HS + d0); GLL(pA0c1, 2 * HS + d1);
  GLL(pA1c0, 3 * HS + d0); GLL(pA1c1, 3 * HS + d1);
  GLL(pB0c0 + BK, 4 * HS + d0); GLL(pB0c1 + BK, 4 * HS + d1);
  GLL(pB1c0 + BK, 5 * HS + d0); GLL(pB1c1 + BK, 5 * HS + d1);
  pB0c0 += 2 * BK; pB0c1 += 2 * BK; pB1c0 += 2 * BK; pB1c1 += 2 * BK;
  pA0c0 += BK;     pA0c1 += BK;     pA1c0 += BK;     pA1c1 += BK;
  WAITV(4);  // tile0 resident; B(tile1) in flight
  BARR;

  // VMODE: 0 -> vmcnt(4), 1 -> vmcnt(0), 2 -> none
#define TILE(P, SA, SB, VMODE) do {                                                        \
    i32x4 af[4], bf0[4], bf1[4];                                                           \
    /* ---- P1: reads a0,b0; stage A0(t+1); MFMA a0 x b0 ---- */                           \
    _Pragma("unroll") for (int i = 0; i < 4; ++i)                                          \
      af[i] = *(const i32x4*)(lds8 + (P) * PS + aB0 + i * 2048);                           \
    _Pragma("unroll") for (int n = 0; n < 4; ++n)                                          \
      bf0[n] = *(const i32x4*)(lds8 + (P) * PS + bB0 + n * 2048);                          \
    if (SA) { GLL(pA0c0, (((P) ^ 1) * 4 + 2) * HS + d0);                                   \
              GLL(pA0c1, (((P) ^ 1) * 4 + 2) * HS + d1);                                   \
              pA0c0 += BK; pA0c1 += BK; }                                                  \
    __builtin_amdgcn_s_setprio(1);                                                         \
    _Pragma("unroll") for (int i = 0; i < 4; ++i)                                          \
      _Pragma("unroll") for (int n = 0; n < 4; ++n)                                        \
        acc[i][n] = __builtin_amdgcn_mfma_i32_16x16x64_i8(af[i], bf0[n], acc[i][n], 0, 0, 0); \
    __builtin_amdgcn_s_setprio(0);                                                         \
    /* ---- P2: reads a1,b1; stage A1(t+1); MFMA a1 x b0; lgkm-drain; MID BARRIER ---- */  \
    _Pragma("unroll") for (int i = 0; i < 4; ++i)                                          \
      af[i] = *(const i32x4*)(lds8 + (P) * PS + aB0 + (4 + i) * 2048);                     \
    _Pragma("unroll") for (int n = 0; n < 4; ++n)                                          \
      bf1[n] = *(const i32x4*)(lds8 + (P) * PS + bB1 + n * 2048);                          \
    if (SA) { GLL(pA1c0, (((P) ^ 1) * 4 + 3) * HS + d0);                                   \
              GLL(pA1c1, (((P) ^ 1) * 4 + 3) * HS + d1);                                   \
              pA1c0 += BK; pA1c1 += BK; }                                                  \
    __builtin_amdgcn_s_setprio(1);                                                         \
    _Pragma("unroll") for (int i = 0; i < 4; ++i)                                          \
      _Pragma("unroll") for (int n = 0; n < 4; ++n)                                        \
        acc[4 + i][n] = __builtin_amdgcn_mfma_i32_16x16x64_i8(af[i], bf0[n], acc[4 + i][n], 0, 0, 0); \
    __builtin_amdgcn_s_setprio(0);                                                         \
    WAITL0;                                                                                \
    BARR;                                                                                  \
    /* ---- P3: reads a2; stage B0(t+2); MFMA a2 x b1 ---- */                              \
    _Pragma("unroll") for (int i = 0; i < 4; ++i)                                          \
      af[i] = *(const i32x4*)(lds8 + (P) * PS + aB1 + i * 2048);                           \
    if (SB) { GLL(pB0c0, ((P) * 4 + 0) * HS + d0);                                         \
              GLL(pB0c1, ((P) * 4 + 0) * HS + d1);                                         \
              pB0c0 += BK; pB0c1 += BK; }                                                  \
    __builtin_amdgcn_s_setprio(1);                                                         \
    _Pragma("unroll") for (int i = 0; i < 4; ++i)                                          \
      _Pragma("unroll") for (int n = 0; n < 4; ++n)                                        \
        acc[i][n] = __builtin_amdgcn_mfma_i32_16x16x64_i8(af[i], bf1[n], acc[i][n], 0, 0, 0); \
    __builtin_amdgcn_s_setprio(0);                                                         \
    /* ---- P4: reads a3; stage B1(t+2); MFMA a3 x b1; WAITV; END BARRIER ---- */          \
    _Pragma("unroll") for (int i = 0; i < 4; ++i)                                          \
      af[i] = *(const i32x4*)(lds8 + (P) * PS + aB1 + (4 + i) * 2048);                     \
    if (SB) { GLL(pB1c0, ((P) * 4 + 1) * HS + d0);                                         \
              GLL(pB1c1, ((P) * 4 + 1) * HS + d1);                                         \
              pB1c0 += BK; pB1c1 += BK; }                                                  \
    __builtin_amdgcn_s_setprio(1);                                                         \
    _Pragma("unroll") for (int i = 0; i < 4; ++i)                                          \
      _Pragma("unroll") for (int n = 0; n < 4; ++n)                                        \
        acc[4 + i][n] = __builtin_amdgcn_mfma_i32_16x16x64_i8(af[i], bf1[n], acc[4 + i][n], 0, 0, 0); \
    __builtin_amdgcn_s_setprio(0);                                                         \
    if ((VMODE) == 0) { WAITV(4); } else if ((VMODE) == 1) { WAITV(0); }                   \
    BARR;                                                                                  \
  } while (0)

  // main loop: tiles 0..29
  for (int it = 0; it < (NTILE - 2) / 2; ++it) {
    TILE(0, 1, 1, 0);
    TILE(1, 1, 1, 0);
  }
  TILE(0, 1, 0, 1);   // tile 30: stage A(31) only; drain
  TILE(1, 0, 0, 2);   // tile 31: no stage, no wait

#undef TILE
#undef GLL

  // epilogue: C/D layout col=lane&15, row=(lane>>4)*4+reg (dtype-independent, validated)
  const int row0 = tm * BM + wm * 128 + lk * 4;
  const int col0 = tn * BN + wn * 64 + lr;
  float sv[4], zv[4];
#pragma unroll
  for (int n = 0; n < 4; ++n) {
    sv[n] = sc[col0 + n * 16];
    zv[n] = 7.5f - zp[col0 + n * 16];
  }
#pragma unroll
  for (int m = 0; m < 8; ++m)
#pragma unroll
    for (int rr = 0; rr < 4; ++rr) {
      const int row = row0 + m * 16 + rr;
      const float rv = rbuf[row];
      const float hx = 0.5f * sxbuf[row];
#pragma unroll
      for (int n = 0; n < 4; ++n)
        C[(size_t)row * N_DIM + col0 + n * 16] = sv[n] * (hx * (float)acc[m][n][rr] + zv[n] * rv);
    }
}

// ---------------- Fallback: fp32 LDS-tiled GEMM reading packed weights (ws too small) ----------------
__global__ __launch_bounds__(256) void fallback_gemm(const float* __restrict__ x,
                                                     const int* __restrict__ pw,
                                                     const float* __restrict__ sc,
                                                     const float* __restrict__ zp,
                                                     float* __restrict__ out) {
  __shared__ float Xs[64][33];
  __shared__ float Ws[64][33];
  const int bid = blockIdx.x;
  const int bm = bid & 63;
  const int bn = bid >> 6;
  const int t = threadIdx.x;
  const int tx = t & 15, ty = t >> 4;
  float acc[4][4] = {};
  for (int k0 = 0; k0 < K_DIM; k0 += 32) {
    __syncthreads();
#pragma unroll
    for (int i = 0; i < 8; ++i) {
      int e = t + i * 256; int r = e >> 5, c = e & 31;
      Xs[r][c] = x[(size_t)(bm * 64 + r) * K_DIM + k0 + c];
    }
#pragma unroll
    for (int i = 0; i < 4; ++i) {
      int e = t + i * 256; int rr = e >> 4, jj = e & 15;
      int row = bn * 64 + rr;
      int v = pw[(size_t)row * KP + (k0 >> 1) + jj];
      float s = sc[row], z = zp[row];
      Ws[rr][2 * jj]     = ((float)(v & 15) - z) * s;
      Ws[rr][2 * jj + 1] = ((float)((v >> 4) & 15) - z) * s;
    }
    __syncthreads();
#pragma unroll
    for (int kk = 0; kk < 32; ++kk) {
      float a[4], b[4];
#pragma unroll
      for (int i2 = 0; i2 < 4; ++i2) a[i2] = Xs[ty * 4 + i2][kk];
#pragma unroll
      for (int j2 = 0; j2 < 4; ++j2) b[j2] = Ws[tx * 4 + j2][kk];
#pragma unroll
      for (int i2 = 0; i2 < 4; ++i2)
#pragma unroll
        for (int j2 = 0; j2 < 4; ++j2) acc[i2][j2] += a[i2] * b[j2];
    }
  }
#pragma unroll
  for (int i2 = 0; i2 < 4; ++i2)
#pragma unroll
    for (int j2 = 0; j2 < 4; ++j2)
      out[(size_t)(bm * 64 + ty * 4 + i2) * N_DIM + bn * 64 + tx * 4 + j2] = acc[i2][j2];
}

extern "C" void kernel_launch(void* const* d_in, const int* in_sizes, int n_in,
                              void* d_out, int out_size, void* d_ws, size_t ws_size,
                              hipStream_t stream) {
  const float* x  = (const float*)d_in[0];
  const int*   pw = (const int*)d_in[1];
  const float* sc = (const float*)d_in[2];
  const float* zp = (const float*)d_in[3];
  float* out = (float*)d_out;

  const size_t wq_b = (size_t)N_DIM * K_DIM;   // 45,088,768
  const size_t xq_b = (size_t)M_DIM * K_DIM;   // 16,777,216
  const size_t need = wq_b + xq_b + 2 * 4096 * sizeof(float);

  if (ws_size >= need) {
    signed char* wq = (signed char*)d_ws;
    signed char* xq = wq + wq_b;
    float* rbuf  = (float*)((char*)d_ws + wq_b + xq_b);
    float* sxbuf = rbuf + 4096;
    hipLaunchKernelGGL(pack_q,  dim3(2048), dim3(256), 0, stream, pw, wq);
    hipLaunchKernelGGL(quant_x, dim3(4096), dim3(256), 0, stream, x, xq, rbuf, sxbuf);
    hipLaunchKernelGGL(gemm_i8, dim3(NWG),  dim3(512), 0, stream, xq, wq, sc, zp, rbuf, sxbuf, out);
  } else {
    hipLaunchKernelGGL(fallback_gemm, dim3(64 * 172), dim3(256), 0, stream, x, pw, sc, zp, out);
  }
}